// Round 3
// baseline (778.452 us; speedup 1.0000x reference)
//
#include <hip/hip_runtime.h>
#include <hip/hip_fp16.h>

// Sizes fixed by the reference problem.
#define HN 128
#define NN 20000
#define GG 32768
#define EE 1000000
#define NSEG (NN + GG)   // 52768
#define TE 128           // edges (or rows) per block tile

typedef _Float16 f16;
typedef __attribute__((ext_vector_type(8))) _Float16 f16x8;
typedef __attribute__((ext_vector_type(4))) float f32x4;

// XOR-swizzled LDS layout for a [TE][HN] f16 tile (row stride 256B).
// Guide G4: row-major 128-wide tiles are a 16/32-way bank conflict on
// ds_read_b128; byte ^= (row&7)<<4 spreads 8 rows over all 32 banks.
__device__ __forceinline__ int swz_h(int row, int col) {
  int b = (row << 8) + (col << 1);
  b ^= (row & 7) << 4;
  return b >> 1;  // half-element index (16B-aligned chunks preserved)
}

__device__ __forceinline__ float silu_f(float x) {
  return x / (1.0f + __expf(-x));
}

__device__ __forceinline__ f32x4 mfma16(f16x8 a, f16x8 b, f32x4 c) {
  return __builtin_amdgcn_mfma_f32_16x16x32_f16(a, b, c, 0, 0, 0);
}

// ---------------------------------------------------------------------------
// Pack f32 weights [K][128] into fp16 MFMA B-fragment order:
//   idx = ((t*KS + s)*64 + lane)*8 + e  ->  W[k][n],
//   k = s*32 + (lane>>4)*8 + e, n = t*16 + (lane&15)
// so each lane's 8 B-values are one contiguous 16B load.
// ---------------------------------------------------------------------------
__global__ void pack_weights(const float* __restrict__ We2,
                             const float* __restrict__ Wm1,
                             const float* __restrict__ Wm2,
                             const float* __restrict__ Wu1,
                             const float* __restrict__ Wu2,
                             f16* __restrict__ dst) {
  const int wid = blockIdx.y;
  const float* src = (wid == 0) ? We2 : (wid == 1) ? Wm1 : (wid == 2) ? Wm2
                    : (wid == 3) ? Wu1 : Wu2;
  const int K   = (wid == 1) ? 256 : 128;
  const int off = (wid == 0) ? 0 : (wid == 1) ? 16384 : (wid == 2) ? 49152
                : (wid == 3) ? 65536 : 81920;
  int p = blockIdx.x * 256 + threadIdx.x;
  if (p >= K * HN) return;
  const int KS = K >> 5;
  int t   = p / (KS * 512);
  int rem = p - t * KS * 512;
  int s   = rem >> 9;
  int q   = rem & 511;
  int lane = q >> 3, e = q & 7;
  int k = s * 32 + ((lane >> 4) << 3) + e;
  int n = (t << 4) + (lane & 15);
  dst[off + p] = (f16)src[k * HN + n];
}

// ---------------------------------------------------------------------------
// Edge kernel: 128 edges/block, 4 waves, each wave owns 32 edge-rows x 128 cols.
// Chain: h1 (VALU) -> GEMM1 (We2) -> GEMM2 ([emb|pe] x Wm1, silu) -> GEMM3 (Wm2)
// -> atomic scatter into out (= seg_sum).  Single 32KB LDS tile reused.
// ---------------------------------------------------------------------------
__global__ __launch_bounds__(256, 2) void edge_kernel(
    const float* __restrict__ emb, const float* __restrict__ npos,
    const float* __restrict__ gpos, const int* __restrict__ eidx,
    const float* __restrict__ frames, const int* __restrict__ batch,
    const float* __restrict__ We1, const float* __restrict__ be1,
    const f16* __restrict__ We2p, const float* __restrict__ be2,
    const f16* __restrict__ Wm1p, const float* __restrict__ bm1,
    const f16* __restrict__ Wm2p, const float* __restrict__ bm2,
    float* __restrict__ out, float* __restrict__ cnt) {
  __shared__ f16 A1[TE * HN];     // 32 KB activation tile (h1 -> pe -> mh)
  __shared__ float sLR[TE * 3];
  __shared__ int sI[TE];
  __shared__ int sJ[TE];

  const int tid = threadIdx.x;
  const int ebase = blockIdx.x * TE;

  // Phase 0: per-edge gather + frame rotation (threads 0..127, 1 edge each)
  if (tid < TE) {
    int eg = ebase + tid;
    bool valid = eg < EE;
    int ec = valid ? eg : (EE - 1);
    int i = eidx[ec];
    int j = eidx[EE + ec];
    int g = j - NN;
    float r0 = gpos[g * 3 + 0] - npos[i * 3 + 0];
    float r1 = gpos[g * 3 + 1] - npos[i * 3 + 1];
    float r2 = gpos[g * 3 + 2] - npos[i * 3 + 2];
    const float* F = frames + batch[i] * 9;
    sLR[tid * 3 + 0] = F[0] * r0 + F[1] * r1 + F[2] * r2;
    sLR[tid * 3 + 1] = F[3] * r0 + F[4] * r1 + F[5] * r2;
    sLR[tid * 3 + 2] = F[6] * r0 + F[7] * r1 + F[8] * r2;
    sI[tid] = i;
    sJ[tid] = valid ? j : -1;
    if (valid) atomicAdd(&cnt[j], 1.0f);
  }
  __syncthreads();

  // Phase 1: h1 = silu(local_rel @ We1 + be1)  (3 FMAs per element)
  for (int idx = tid; idx < TE * HN; idx += 256) {
    int e = idx >> 7, h = idx & (HN - 1);
    float x = sLR[e * 3 + 0] * We1[h] + sLR[e * 3 + 1] * We1[HN + h] +
              sLR[e * 3 + 2] * We1[2 * HN + h] + be1[h];
    A1[swz_h(e, h)] = (f16)silu_f(x);
  }
  __syncthreads();

  const int lane = tid & 63;
  const int w = tid >> 6;
  const int lr_ = lane & 15;      // A row / C col within 16-tile
  const int hi = lane >> 4;       // k-group / C row-group
  const int r0w = w * 32;         // this wave's edge-row base

  f32x4 acc[2][8];

  // ---- GEMM1: pos_emb = h1 @ We2 + be2
  {
    f16x8 a[2][4];
#pragma unroll
    for (int mt = 0; mt < 2; mt++)
#pragma unroll
      for (int s = 0; s < 4; s++)
        a[mt][s] = *(const f16x8*)(A1 + swz_h(r0w + mt * 16 + lr_, s * 32 + hi * 8));
#pragma unroll
    for (int t = 0; t < 8; t++) {
      float bv = be2[t * 16 + lr_];
      acc[0][t] = (f32x4){bv, bv, bv, bv};
      acc[1][t] = (f32x4){bv, bv, bv, bv};
    }
#pragma unroll
    for (int t = 0; t < 8; t++)
#pragma unroll
      for (int s = 0; s < 4; s++) {
        f16x8 b = *(const f16x8*)(We2p + (size_t)((t * 4 + s) * 64 + lane) * 8);
        acc[0][t] = mfma16(a[0][s], b, acc[0][t]);
        acc[1][t] = mfma16(a[1][s], b, acc[1][t]);
      }
  }
  __syncthreads();
#pragma unroll
  for (int mt = 0; mt < 2; mt++)
#pragma unroll
    for (int t = 0; t < 8; t++)
#pragma unroll
      for (int r = 0; r < 4; r++)
        A1[swz_h(r0w + mt * 16 + hi * 4 + r, t * 16 + lr_)] = (f16)acc[mt][t][r];
  __syncthreads();

  // ---- GEMM2: mh = silu([emb_i | pos_emb] @ Wm1 + bm1)
  {
    f16x8 aq[2][4];  // pos_emb fragments from LDS
    f16x8 ae[2][4];  // embedding fragments straight from global (L2-resident)
#pragma unroll
    for (int mt = 0; mt < 2; mt++) {
#pragma unroll
      for (int s = 0; s < 4; s++)
        aq[mt][s] = *(const f16x8*)(A1 + swz_h(r0w + mt * 16 + lr_, s * 32 + hi * 8));
      const float* ep = emb + (size_t)sI[r0w + mt * 16 + lr_] * HN + hi * 8;
#pragma unroll
      for (int s = 0; s < 4; s++) {
        float4 v0 = *reinterpret_cast<const float4*>(ep + s * 32);
        float4 v1 = *reinterpret_cast<const float4*>(ep + s * 32 + 4);
        f16x8 a;
        a[0] = (f16)v0.x; a[1] = (f16)v0.y; a[2] = (f16)v0.z; a[3] = (f16)v0.w;
        a[4] = (f16)v1.x; a[5] = (f16)v1.y; a[6] = (f16)v1.z; a[7] = (f16)v1.w;
        ae[mt][s] = a;
      }
    }
#pragma unroll
    for (int t = 0; t < 8; t++) {
      float bv = bm1[t * 16 + lr_];
      acc[0][t] = (f32x4){bv, bv, bv, bv};
      acc[1][t] = (f32x4){bv, bv, bv, bv};
    }
#pragma unroll
    for (int t = 0; t < 8; t++)
#pragma unroll
      for (int s = 0; s < 8; s++) {
        f16x8 b = *(const f16x8*)(Wm1p + (size_t)((t * 8 + s) * 64 + lane) * 8);
        f16x8 a0 = (s < 4) ? ae[0][s & 3] : aq[0][s & 3];
        f16x8 a1 = (s < 4) ? ae[1][s & 3] : aq[1][s & 3];
        acc[0][t] = mfma16(a0, b, acc[0][t]);
        acc[1][t] = mfma16(a1, b, acc[1][t]);
      }
  }
  __syncthreads();
#pragma unroll
  for (int mt = 0; mt < 2; mt++)
#pragma unroll
    for (int t = 0; t < 8; t++)
#pragma unroll
      for (int r = 0; r < 4; r++)
        A1[swz_h(r0w + mt * 16 + hi * 4 + r, t * 16 + lr_)] = (f16)silu_f(acc[mt][t][r]);
  __syncthreads();

  // ---- GEMM3: msg = mh @ Wm2 + bm2
  {
    f16x8 a[2][4];
#pragma unroll
    for (int mt = 0; mt < 2; mt++)
#pragma unroll
      for (int s = 0; s < 4; s++)
        a[mt][s] = *(const f16x8*)(A1 + swz_h(r0w + mt * 16 + lr_, s * 32 + hi * 8));
#pragma unroll
    for (int t = 0; t < 8; t++) {
      float bv = bm2[t * 16 + lr_];
      acc[0][t] = (f32x4){bv, bv, bv, bv};
      acc[1][t] = (f32x4){bv, bv, bv, bv};
    }
#pragma unroll
    for (int t = 0; t < 8; t++)
#pragma unroll
      for (int s = 0; s < 4; s++) {
        f16x8 b = *(const f16x8*)(Wm2p + (size_t)((t * 4 + s) * 64 + lane) * 8);
        acc[0][t] = mfma16(a[0][s], b, acc[0][t]);
        acc[1][t] = mfma16(a[1][s], b, acc[1][t]);
      }
  }

  // Scatter-add msg into out (= segment sums)
#pragma unroll
  for (int mt = 0; mt < 2; mt++) {
#pragma unroll
    for (int r = 0; r < 4; r++) {
      int row = r0w + mt * 16 + hi * 4 + r;
      int j = sJ[row];
      if (j >= 0) {
        float* dst = out + (size_t)j * HN + lr_;
#pragma unroll
        for (int t = 0; t < 8; t++)
          atomicAdd(dst + t * 16, acc[mt][t][r]);
      }
    }
  }
}

// ---------------------------------------------------------------------------
// Finalize: mean = out/max(cnt,1); out = silu(mean@Wu1+bu1)@Wu2+bu2, in place.
// Row-local, so in-place is safe (each block reads only its own rows, then
// writes after a barrier).
// ---------------------------------------------------------------------------
__global__ __launch_bounds__(256, 2) void finalize_kernel(
    float* __restrict__ out, const float* __restrict__ cnt,
    const f16* __restrict__ Wu1p, const float* __restrict__ bu1,
    const f16* __restrict__ Wu2p, const float* __restrict__ bu2) {
  __shared__ f16 A1[TE * HN];
  const int tid = threadIdx.x;
  const int rbase = blockIdx.x * TE;

  for (int idx = tid; idx < TE * HN; idx += 256) {
    int e = idx >> 7, h = idx & (HN - 1);
    int row = rbase + e;
    float v = 0.0f;
    if (row < NSEG) v = out[(size_t)row * HN + h] / fmaxf(cnt[row], 1.0f);
    A1[swz_h(e, h)] = (f16)v;
  }
  __syncthreads();

  const int lane = tid & 63;
  const int w = tid >> 6;
  const int lr_ = lane & 15;
  const int hi = lane >> 4;
  const int r0w = w * 32;

  f32x4 acc[2][8];

  // GEMM A: hidden = silu(mean @ Wu1 + bu1)
  {
    f16x8 a[2][4];
#pragma unroll
    for (int mt = 0; mt < 2; mt++)
#pragma unroll
      for (int s = 0; s < 4; s++)
        a[mt][s] = *(const f16x8*)(A1 + swz_h(r0w + mt * 16 + lr_, s * 32 + hi * 8));
#pragma unroll
    for (int t = 0; t < 8; t++) {
      float bv = bu1[t * 16 + lr_];
      acc[0][t] = (f32x4){bv, bv, bv, bv};
      acc[1][t] = (f32x4){bv, bv, bv, bv};
    }
#pragma unroll
    for (int t = 0; t < 8; t++)
#pragma unroll
      for (int s = 0; s < 4; s++) {
        f16x8 b = *(const f16x8*)(Wu1p + (size_t)((t * 4 + s) * 64 + lane) * 8);
        acc[0][t] = mfma16(a[0][s], b, acc[0][t]);
        acc[1][t] = mfma16(a[1][s], b, acc[1][t]);
      }
  }
  __syncthreads();
#pragma unroll
  for (int mt = 0; mt < 2; mt++)
#pragma unroll
    for (int t = 0; t < 8; t++)
#pragma unroll
      for (int r = 0; r < 4; r++)
        A1[swz_h(r0w + mt * 16 + hi * 4 + r, t * 16 + lr_)] = (f16)silu_f(acc[mt][t][r]);
  __syncthreads();

  // GEMM B: out = hidden @ Wu2 + bu2
  {
    f16x8 a[2][4];
#pragma unroll
    for (int mt = 0; mt < 2; mt++)
#pragma unroll
      for (int s = 0; s < 4; s++)
        a[mt][s] = *(const f16x8*)(A1 + swz_h(r0w + mt * 16 + lr_, s * 32 + hi * 8));
#pragma unroll
    for (int t = 0; t < 8; t++) {
      float bv = bu2[t * 16 + lr_];
      acc[0][t] = (f32x4){bv, bv, bv, bv};
      acc[1][t] = (f32x4){bv, bv, bv, bv};
    }
#pragma unroll
    for (int t = 0; t < 8; t++)
#pragma unroll
      for (int s = 0; s < 4; s++) {
        f16x8 b = *(const f16x8*)(Wu2p + (size_t)((t * 4 + s) * 64 + lane) * 8);
        acc[0][t] = mfma16(a[0][s], b, acc[0][t]);
        acc[1][t] = mfma16(a[1][s], b, acc[1][t]);
      }
  }
#pragma unroll
  for (int mt = 0; mt < 2; mt++)
#pragma unroll
    for (int t = 0; t < 8; t++)
#pragma unroll
      for (int r = 0; r < 4; r++) {
        int row = rbase + r0w + mt * 16 + hi * 4 + r;
        if (row < NSEG) out[(size_t)row * HN + t * 16 + lr_] = acc[mt][t][r];
      }
}

extern "C" void kernel_launch(void* const* d_in, const int* in_sizes, int n_in,
                              void* d_out, int out_size, void* d_ws, size_t ws_size,
                              hipStream_t stream) {
  const float* emb    = (const float*)d_in[0];
  const float* npos   = (const float*)d_in[1];
  const float* gpos   = (const float*)d_in[2];
  const int*   eidx   = (const int*)d_in[3];
  const float* frames = (const float*)d_in[4];
  const int*   batch  = (const int*)d_in[5];
  const float* We1 = (const float*)d_in[6];
  const float* be1 = (const float*)d_in[7];
  const float* We2 = (const float*)d_in[8];
  const float* be2 = (const float*)d_in[9];
  const float* Wm1 = (const float*)d_in[10];
  const float* bm1 = (const float*)d_in[11];
  const float* Wm2 = (const float*)d_in[12];
  const float* bm2 = (const float*)d_in[13];
  const float* Wu1 = (const float*)d_in[14];
  const float* bu1 = (const float*)d_in[15];
  const float* Wu2 = (const float*)d_in[16];
  const float* bu2 = (const float*)d_in[17];

  float* out = (float*)d_out;
  float* cnt = (float*)d_ws;                       // NSEG floats
  f16* wp    = (f16*)((char*)d_ws + 262144);       // packed fp16 weights
  f16* We2p  = wp;
  f16* Wm1p  = wp + 16384;
  f16* Wm2p  = wp + 49152;
  f16* Wu1p  = wp + 65536;
  f16* Wu2p  = wp + 81920;

  hipMemsetAsync(d_out, 0, (size_t)NSEG * HN * sizeof(float), stream);
  hipMemsetAsync(cnt, 0, (size_t)NSEG * sizeof(float), stream);

  pack_weights<<<dim3(128, 5), 256, 0, stream>>>(We2, Wm1, Wm2, Wu1, Wu2, wp);

  int eblocks = (EE + TE - 1) / TE;                // 7813
  edge_kernel<<<eblocks, 256, 0, stream>>>(
      emb, npos, gpos, eidx, frames, batch, We1, be1, We2p, be2, Wm1p, bm1,
      Wm2p, bm2, out, cnt);

  int fblocks = (NSEG + TE - 1) / TE;              // 413
  finalize_kernel<<<fblocks, 256, 0, stream>>>(out, cnt, Wu1p, bu1, Wu2p, bu2);
}